// Round 4
// baseline (158.548 us; speedup 1.0000x reference)
//
#include <hip/hip_runtime.h>
#include <math.h>

// EqualtimeLayer R17 = R16 with the two measured stall sources removed.
// R16 post-mortem: issue count == R13 but stalls grew (104us vs 78.7):
//  (1) hist did atomicAdd+atomicMin per event (LDS conflicts 2.06M->2.77M),
//  (2) wave-0 bucket-suffix used a serial ds_bpermute chain at B2.
// Fix: positions are bucket-ordered after scatter, so "min time over later
// buckets" == positional suffix-min of s_t. Compute it IN the solve phase:
// reverse-shuffle + DPP min-scan on the t_p each thread already loaded,
// one s_psx[p] write + per-wave min in s_fmn, sharing the existing partials
// barrier. Reader at q=bas+cn combines s_psx[q] with later waves' s_fmn.
// Deleted: 4x atomicMin, bucket-suffix machinery, s_minT/s_sfx + re-inits.
// Fast path (N_low <= 256, dominant): 5 barriers/batch, fully fused.
// Generic path (N_low > 256 or fallback tail, rare): suffix pre-pass over
// chunks in reverse, then the R16-style chunked solve reading s_psx. Exact.

#define B_TOT 32
#define PRE 1024
#define POST 1024
#define NB 512
#define TPB 256
#define EPT 4
#define BPW 8
#define CHUNK 256
#define TCUTF 0.625f
#define BSCALE 819.2f          // 512 buckets over [0, 0.625)
#define BSCALE2 372.36363636f  // 512 buckets over [0.625, 2.0)
#define INFB 0x7F800000

// ---- DPP helpers (gfx9 encodings) ----
template<int CTRL, int MASK>
__device__ __forceinline__ int dpp_add_i32(int v) {
    return v + __builtin_amdgcn_update_dpp(0, v, CTRL, MASK, 0xf, true);
}
template<int CTRL, int MASK>
__device__ __forceinline__ float dpp_add_f32(float v) {
    int t = __builtin_amdgcn_update_dpp(0, __float_as_int(v), CTRL, MASK, 0xf, true);
    return v + __int_as_float(t);
}
template<int CTRL, int MASK>
__device__ __forceinline__ int dpp_min_i32(int v) {
    // old = +INF bits, bound_ctrl=false: missing lanes contribute min identity
    int t = __builtin_amdgcn_update_dpp(INFB, v, CTRL, MASK, 0xf, false);
    return min(v, t);
}
template<int CTRL>
__device__ __forceinline__ float dpp_min_f32(float v) {
    int t = __builtin_amdgcn_update_dpp(__float_as_int(v), __float_as_int(v), CTRL, 0xf, 0xf, false);
    return fminf(v, __int_as_float(t));
}
__device__ __forceinline__ int wave_iscan_i32(int v) {
    v = dpp_add_i32<0x111, 0xf>(v);
    v = dpp_add_i32<0x112, 0xf>(v);
    v = dpp_add_i32<0x114, 0xf>(v);
    v = dpp_add_i32<0x118, 0xf>(v);
    v = dpp_add_i32<0x142, 0xa>(v);
    v = dpp_add_i32<0x143, 0xc>(v);
    return v;
}
__device__ __forceinline__ float wave_iscan_f32(float v) {
    v = dpp_add_f32<0x111, 0xf>(v);
    v = dpp_add_f32<0x112, 0xf>(v);
    v = dpp_add_f32<0x114, 0xf>(v);
    v = dpp_add_f32<0x118, 0xf>(v);
    v = dpp_add_f32<0x142, 0xa>(v);
    v = dpp_add_f32<0x143, 0xc>(v);
    return v;
}
__device__ __forceinline__ int wave_iscan_min_i32(int v) {
    v = dpp_min_i32<0x111, 0xf>(v);
    v = dpp_min_i32<0x112, 0xf>(v);
    v = dpp_min_i32<0x114, 0xf>(v);
    v = dpp_min_i32<0x118, 0xf>(v);
    v = dpp_min_i32<0x142, 0xa>(v);
    v = dpp_min_i32<0x143, 0xc>(v);
    return v;
}
__device__ __forceinline__ float wave_min_f32(float v) {
    v = fminf(v, __shfl_down(v, 32));
    v = fminf(v, __shfl_down(v, 16));
    v = dpp_min_f32<0x140>(v);
    v = dpp_min_f32<0x141>(v);
    v = dpp_min_f32<0x4E>(v);
    v = dpp_min_f32<0xB1>(v);
    return v;
}
// In-wave INCLUSIVE suffix-min of t (>=0) over lanes >= own lane.
// t>=0 => float order == int-bit order.
__device__ __forceinline__ float wave_suffix_min_f32(float t, int lane) {
    int rv = __shfl(__float_as_int(t), 63 - lane);   // reverse
    int is = wave_iscan_min_i32(rv);                 // inclusive fwd min
    return __int_as_float(__shfl(is, 63 - lane));    // reverse back
}
__device__ __forceinline__ int clampb(int k) {
    return k < 0 ? 0 : (k > NB - 1 ? NB - 1 : k);
}

// Wave-0-only: exclusive scan of NB counts (raw -> pck, packed off<<12|cnt),
// total -> *nout. Conflict-free int4 layout at [lane]/[lane+64] (R13-proven).
__device__ __forceinline__ void scan_counts(const int* raw, int* pck,
                                            int* nout, int lane) {
    int4 a = reinterpret_cast<const int4*>(raw)[lane];
    int4 b = reinterpret_cast<const int4*>(raw)[lane + 64];
    int c1[4] = {a.x, a.y, a.z, a.w};
    int c2[4] = {b.x, b.y, b.z, b.w};
    int ls1[4], ls2[4];
    int s1 = 0, s2 = 0;
#pragma unroll
    for (int j = 0; j < 4; ++j) { s1 += c1[j]; ls1[j] = s1; }
#pragma unroll
    for (int j = 0; j < 4; ++j) { s2 += c2[j]; ls2[j] = s2; }
    int x1 = wave_iscan_i32(s1);
    int x2 = wave_iscan_i32(s2);
    int tot1 = __builtin_amdgcn_readlane(x1, 63);
    int tot2 = __builtin_amdgcn_readlane(x2, 63);
    int e1 = x1 - s1;
    int e2 = tot1 + x2 - s2;
    int o1[4], o2[4];
#pragma unroll
    for (int j = 0; j < 4; ++j) {
        o1[j] = ((e1 + ls1[j] - c1[j]) << 12) | c1[j];
        o2[j] = ((e2 + ls2[j] - c2[j]) << 12) | c2[j];
    }
    reinterpret_cast<int4*>(pck)[lane]      = make_int4(o1[0], o1[1], o1[2], o1[3]);
    reinterpret_cast<int4*>(pck)[lane + 64] = make_int4(o2[0], o2[1], o2[2], o2[3]);
    if (lane == 0) *nout = tot1 + tot2;
}

// Generic positional suffix-min pre-pass: s_psx[p] = min s_t[p..cEnd) for
// p in [cStart, cEnd). Reverse chunk order, carry across chunks. Rare path.
__device__ __forceinline__ void build_suffix(const float* s_t, float* s_psx,
                                             float* s_fmn,
                                             int cStart, int cEnd,
                                             int tid, int lane, int wid) {
    float carry = INFINITY;
    for (int c0 = cEnd - CHUNK; c0 >= cStart; c0 -= CHUNK) {
        int p = c0 + tid;
        float sx = wave_suffix_min_f32(s_t[p], lane);
        if (lane == 0) s_fmn[wid] = sx;
        __syncthreads();                               // partial mins visible
        float v = fminf(sx, carry);
        for (int w = wid + 1; w < 4; ++w) v = fminf(v, s_fmn[w]);
        s_psx[p] = v;
        carry = fminf(carry, fminf(fminf(s_fmn[0], s_fmn[1]),
                                   fminf(s_fmn[2], s_fmn[3])));
        __syncthreads();                               // psx + s_fmn reuse safe
    }
}

// Generic chunked solver (rare path: N_low > 256 or fallback tail).
// Position-order block scans + mates correction; tnx from s_psx.
__device__ __forceinline__ void solve_generic(
    const float* s_t, const float* s_w, const int* pck, const float* s_psx,
    float* s_fw, float* s_fwt,
    int cStart, int cEnd, int posLo, int posValidEnd,
    float t0f, float bscale, int baseOff, float tEnd, float theta,
    int tid, int lane, int wid, float& cumW, float& cumWT, float& mloc)
{
    for (int c0 = cStart; c0 < cEnd; c0 += CHUNK) {
        int p = c0 + tid;
        float t_p = s_t[p];
        float w_p = (p >= posLo) ? s_w[p] : 0.f;
        float xw  = wave_iscan_f32(w_p);
        float xwt = wave_iscan_f32(w_p * t_p);
        if (lane == 63) { s_fw[wid] = xw; s_fwt[wid] = xwt; }
        __syncthreads();                               // partials visible
        float W = cumW, WT = cumWT;
        for (int k2 = 0; k2 < wid; ++k2) { W += s_fw[k2]; WT += s_fwt[k2]; }
        W += xw; WT += xwt;                            // inclusive @ p (pos order)
        cumW  += s_fw[0] + s_fw[1] + s_fw[2] + s_fw[3];
        cumWT += s_fwt[0] + s_fwt[1] + s_fwt[2] + s_fwt[3];

        if (p >= posLo && p < posValidEnd) {
            int k = clampb((int)((t_p - t0f) * bscale));
            int pk = pck[k];
            int bas = (pk >> 12) + baseOff, cn = pk & 0xfff;
            int q = bas + cn;
            float tnx = (q < cEnd) ? s_psx[q] : tEnd;
            tnx = fminf(tnx, tEnd);
            if (cn > 1) {
                for (int q2 = bas; q2 < bas + cn; ++q2) {
                    if (q2 == p) continue;
                    float tq = s_t[q2], wq = s_w[q2];
                    bool earlier = (tq < t_p) || (tq == t_p && q2 < p);
                    bool posb = (q2 < p);
                    W  += (earlier ? wq      : 0.f) - (posb ? wq      : 0.f);
                    WT += (earlier ? wq * tq : 0.f) - (posb ? wq * tq : 0.f);
                    if (!earlier) tnx = fminf(tnx, tq);
                }
            }
            if (W > 0.f) {
                float tmp = (theta + WT) * __builtin_amdgcn_rcpf(W);
                if (tmp >= t_p && tmp <= tnx) mloc = fminf(mloc, tmp);
            }
        }
        if (c0 + CHUNK < cEnd) __syncthreads();        // protect s_fw reuse
    }
}

__device__ __forceinline__ float block_min(float v, float* s_red, int lane, int wid) {
    v = wave_min_f32(v);
    if (lane == 0) s_red[wid] = v;
    __syncthreads();
    return fminf(fminf(s_red[0], s_red[1]), fminf(s_red[2], s_red[3]));
}

__global__ __launch_bounds__(TPB, 6) void equaltime_kernel(
    const float* __restrict__ spikes,     // [B][PRE]
    const float* __restrict__ weights,    // [PRE][POST]
    const float* __restrict__ delays,     // [PRE][POST]
    const float* __restrict__ thresholds, // [POST]
    float* __restrict__ out)              // [B][POST]
{
    __shared__ __align__(16) float s_t[PRE];    // 4 KB
    __shared__ __align__(16) float s_w[PRE];    // 4 KB
    __shared__ __align__(16) int   s_raw[NB];   // 2 KB counts
    __shared__ __align__(16) int   s_pck[NB];   // 2 KB packed (off<<12|cnt)
    __shared__ __align__(16) float s_psx[PRE];  // 4 KB positional suffix-min
    __shared__ float s_fw[4], s_fwt[4], s_fmn[4];
    __shared__ float s_red[4];
    __shared__ int   s_nlow;

    const int tid  = threadIdx.x;
    const int lane = tid & 63;
    const int wid  = tid >> 6;

    // XCD-contiguous swizzle for weight/delay L2 locality
    const int bx   = blockIdx.x;
    const int sbx  = (bx & 7) * 512 + (bx >> 3);
    const int post = sbx >> 2;            // 4 WGs per post
    const int b0   = (sbx & 3) * BPW;
    const float theta = thresholds[post];

    float dly[EPT], wgt[EPT];
#pragma unroll
    for (int j = 0; j < EPT; ++j) {
        int pre = tid * EPT + j;
        dly[j] = delays[pre * POST + post];
        wgt[j] = weights[pre * POST + post];
    }

    // init counts once (re-inits folded into each batch's scatter phase)
    if (tid < 128)
        reinterpret_cast<int4*>(s_raw)[tid] = make_int4(0, 0, 0, 0);
    __syncthreads();

    for (int bi = 0; bi < BPW; ++bi) {
        const int b = b0 + bi;

        // ---- times; hist (count only) of t<TCUT; min of the rest ----
        float4 sp = *reinterpret_cast<const float4*>(spikes + b * PRE + tid * EPT);
        float tv[EPT] = {sp.x + dly[0], sp.y + dly[1], sp.z + dly[2], sp.w + dly[3]};
        int bkt[EPT], rnk[EPT];
        float mloc = INFINITY;
#pragma unroll
        for (int j = 0; j < EPT; ++j) {
            int k = (int)(tv[j] * BSCALE);
            bkt[j] = k;
            if (k < NB) rnk[j] = atomicAdd(&s_raw[k], 1);
            else        mloc = fminf(mloc, tv[j]);
        }
        mloc = wave_min_f32(mloc);
        __syncthreads();                               // B1: hist final

        if (lane == 0) s_red[wid] = mloc;              // read post-B2
        if (wid == 0) scan_counts(s_raw, s_pck, &s_nlow, lane);
        __syncthreads();                               // B2: pck/nlow/s_red

        const int N_low = s_nlow;
        const float minExcl = fminf(fminf(s_red[0], s_red[1]),
                                    fminf(s_red[2], s_red[3]));

        // ---- scatter (arrival order in bucket); zero raw; pad holes ----
#pragma unroll
        for (int j = 0; j < EPT; ++j) {
            if (bkt[j] < NB) {
                int pos = (s_pck[bkt[j]] >> 12) + rnk[j];
                s_t[pos] = tv[j];
                s_w[pos] = wgt[j];
            }
        }
        if (wid == 1) {   // s_raw reads done at B2; contiguous zero
            reinterpret_cast<int4*>(s_raw)[lane]      = make_int4(0, 0, 0, 0);
            reinterpret_cast<int4*>(s_raw)[lane + 64] = make_int4(0, 0, 0, 0);
        }
        const int roundup = (N_low + CHUNK - 1) & ~(CHUNK - 1);
        int h = N_low + tid;
        if (h < roundup) { s_t[h] = minExcl; s_w[h] = 0.f; }
        __syncthreads();                               // B3: scatter+zero visible

        float cumW = 0.f, cumWT = 0.f, mcand = INFINITY;

        if (roundup == CHUNK) {
            // ==== fused fast path: one chunk, suffix fused into scan ====
            const int p = tid;
            float t_p = s_t[p];
            float w_p = s_w[p];                        // pad has w=0
            float xw  = wave_iscan_f32(w_p);
            float xwt = wave_iscan_f32(w_p * t_p);
            float sx  = wave_suffix_min_f32(t_p, lane);
            s_psx[p] = sx;                             // in-wave suffix only
            if (lane == 63) { s_fw[wid] = xw; s_fwt[wid] = xwt; }
            if (lane == 0)  s_fmn[wid] = sx;           // wave's total min
            __syncthreads();                           // B4: partials+psx

            float W = 0.f, WT = 0.f;
            for (int k2 = 0; k2 < wid; ++k2) { W += s_fw[k2]; WT += s_fwt[k2]; }
            W += xw; WT += xwt;
            cumW  = s_fw[0] + s_fw[1] + s_fw[2] + s_fw[3];
            cumWT = s_fwt[0] + s_fwt[1] + s_fwt[2] + s_fwt[3];

            if (p < N_low) {
                int k = (int)(t_p * BSCALE);           // real event => k < NB
                int pk = s_pck[k];
                int bas = pk >> 12, cn = pk & 0xfff;
                int q = bas + cn;
                float tnx = minExcl;
                if (q < CHUNK) {
                    float v = s_psx[q];                // covers q..wave-end
                    for (int w = (q >> 6) + 1; w < 4; ++w)
                        v = fminf(v, s_fmn[w]);        // later waves
                    tnx = fminf(v, minExcl);
                }
                if (cn > 1) {
                    for (int q2 = bas; q2 < bas + cn; ++q2) {
                        if (q2 == p) continue;
                        float tq = s_t[q2], wq = s_w[q2];
                        bool earlier = (tq < t_p) || (tq == t_p && q2 < p);
                        bool posb = (q2 < p);
                        W  += (earlier ? wq      : 0.f) - (posb ? wq      : 0.f);
                        WT += (earlier ? wq * tq : 0.f) - (posb ? wq * tq : 0.f);
                        if (!earlier) tnx = fminf(tnx, tq);
                    }
                }
                if (W > 0.f) {
                    float tmp = (theta + WT) * __builtin_amdgcn_rcpf(W);
                    if (tmp >= t_p && tmp <= tnx) mcand = tmp;
                }
            }
        } else {
            // ==== generic path (N_low > 256, ~1e-5 probability): exact ====
            build_suffix(s_t, s_psx, s_fmn, 0, roundup, tid, lane, wid);
            solve_generic(s_t, s_w, s_pck, s_psx, s_fw, s_fwt,
                          0, roundup, 0, N_low, 0.f, BSCALE, 0, minExcl, theta,
                          tid, lane, wid, cumW, cumWT, mcand);
        }
        float mAll = block_min(mcand, s_red, lane, wid);  // B5

        // ---- rare exact fallback: no valid crossing among t < TCUT ----
        if (!(mAll < INFINITY) && N_low < PRE) {
#pragma unroll
            for (int j = 0; j < EPT; ++j) {
                if (bkt[j] >= NB) {
                    int k2 = clampb((int)((tv[j] - TCUTF) * BSCALE2));
                    bkt[j] = NB + k2;                  // remember tail bucket
                    rnk[j] = atomicAdd(&s_raw[k2], 1);
                }
            }
            __syncthreads();                           // tail hist final
            if (wid == 0) scan_counts(s_raw, s_pck, &s_nlow, lane);
            __syncthreads();                           // pck visible
#pragma unroll
            for (int j = 0; j < EPT; ++j) {
                if (bkt[j] >= NB) {
                    int pos = N_low + (s_pck[bkt[j] - NB] >> 12) + rnk[j];
                    s_t[pos] = tv[j];
                    s_w[pos] = wgt[j];
                }
            }
            if (wid == 1) {   // re-zero for next batch
                reinterpret_cast<int4*>(s_raw)[lane]      = make_int4(0, 0, 0, 0);
                reinterpret_cast<int4*>(s_raw)[lane + 64] = make_int4(0, 0, 0, 0);
            }
            __syncthreads();                           // scatter+zero visible
            const int cStart2 = N_low & ~(CHUNK - 1);
            build_suffix(s_t, s_psx, s_fmn, cStart2, PRE, tid, lane, wid);
            solve_generic(s_t, s_w, s_pck, s_psx, s_fw, s_fwt,
                          cStart2, PRE, N_low, PRE,
                          TCUTF, BSCALE2, N_low, INFINITY, theta,
                          tid, lane, wid, cumW, cumWT, mcand);
            mAll = block_min(mcand, s_red, lane, wid);
        }

        if (tid == 0) out[b * POST + post] = mAll;
        // No trailing barrier: next batch's hist atomics target s_raw, whose
        // zeroing was barrier-ordered before any post-barrier reader.
    }
}

extern "C" void kernel_launch(void* const* d_in, const int* in_sizes, int n_in,
                              void* d_out, int out_size, void* d_ws, size_t ws_size,
                              hipStream_t stream) {
    const float* spikes     = (const float*)d_in[0]; // [32,1024]
    const float* weights    = (const float*)d_in[1]; // [1024,1024]
    const float* delays     = (const float*)d_in[2]; // [1024,1024]
    const float* thresholds = (const float*)d_in[3]; // [1024]
    float* outp = (float*)d_out;                     // [32,1024]

    dim3 grid(POST * (B_TOT / BPW)); // 4096 workgroups
    dim3 block(TPB);
    equaltime_kernel<<<grid, block, 0, stream>>>(spikes, weights, delays, thresholds, outp);
}